// Round 8
// baseline (1192.961 us; speedup 1.0000x reference)
//
#include <hip/hip_runtime.h>
#include <hip/hip_bf16.h>
#include <cmath>

typedef __hip_bfloat16 bf16;
typedef short short8 __attribute__((ext_vector_type(8)));   // 8 bf16 (4 VGPRs)
typedef float f32x4  __attribute__((ext_vector_type(4)));   // MFMA acc

#define Cc    180
#define KP1   192      // 180 padded to mult of 32
#define KP2   768      // 720 padded to 4 chunks of 192
#define Hh    112
#define Wwid  112
#define Ltok  12544
#define Bsz   2
#define TOK   25088
#define WSz   7
#define NHd   6
#define DHd   30
#define NWIN  256
#define P49   49

// Dual-dtype input access: flag==1 -> float32 inputs, flag==0 -> bf16.
__device__ __forceinline__ float LD(const void* p, size_t i, int f) {
    if (f) return ((const float*)p)[i];
    return (float)((const bf16*)p)[i];
}
__device__ __forceinline__ void ST(void* p, size_t i, int f, float v) {
    if (f) ((float*)p)[i] = v;
    else   ((bf16*)p)[i] = (bf16)v;
}

__device__ __forceinline__ float wred(float v) {
    v += __shfl_xor(v, 1);
    v += __shfl_xor(v, 2);
    v += __shfl_xor(v, 4);
    v += __shfl_xor(v, 8);
    v += __shfl_xor(v, 16);
    v += __shfl_xor(v, 32);
    return v;
}

// ---- dtype detect (bf16 N(0,1) never has exponent >= 0xC8) -----------------
__global__ void k_detect(const unsigned short* __restrict__ xb, int* __restrict__ flag) {
    __shared__ int s;
    if (threadIdx.x == 0) s = 0;
    __syncthreads();
    int bad = 0;
    for (int i = threadIdx.x; i < 2048; i += 256) {
        int e = (xb[i] >> 7) & 0xFF;
        if (e >= 0xC8) bad = 1;
    }
    if (bad) atomicOr(&s, 1);
    __syncthreads();
    if (threadIdx.x == 0) flag[0] = s;
}

// ---- weight transpose+pad: dst(Npad x Kp) <- src(K x N), zeros outside -----
__global__ __launch_bounds__(256) void k_tr(const void* __restrict__ src, size_t woff,
                                            bf16* __restrict__ dst,
                                            int K, int N, int Kp, int Npad,
                                            const int* __restrict__ dflag) {
    int f = *dflag;
    int idx = blockIdx.x * 256 + threadIdx.x;
    if (idx >= Npad * Kp) return;
    int n = idx / Kp, k = idx % Kp;
    float v = (n < N && k < K) ? LD(src, woff + (size_t)k * N + n, f) : 0.f;
    dst[idx] = (bf16)v;
}

// ---- qkv weight transpose with head-padded column remap --------------------
__global__ __launch_bounds__(256) void k_trq(const void* __restrict__ src, size_t woff,
                                             bf16* __restrict__ dst,
                                             const int* __restrict__ dflag) {
    int f = *dflag;
    int idx = blockIdx.x * 256 + threadIdx.x;
    if (idx >= 576 * KP1) return;
    int n = idx / KP1, k = idx % KP1;
    int sec = n / 192, rm = n % 192, hd = rm >> 5, d = rm & 31;
    float v = (d < 30 && k < 180) ? LD(src, woff + (size_t)k * 540 + sec * 180 + hd * 30 + d, f) : 0.f;
    dst[idx] = (bf16)v;
}

// ---- rpb expand: BT[6][64][64] f32, -1e9 in pads ---------------------------
__global__ __launch_bounds__(256) void k_bias(const void* __restrict__ rpb, size_t off,
                                              float* __restrict__ BT,
                                              const int* __restrict__ dflag) {
    int f = *dflag;
    int idx = blockIdx.x * 256 + threadIdx.x;
    if (idx >= NHd * 4096) return;
    int hd = idx >> 12, rem = idx & 4095;
    int i = rem >> 6, j = rem & 63;
    float v;
    if (i < 49 && j < 49) {
        int rel = (i / 7 - j / 7 + 6) * 13 + (i % 7 - j % 7 + 6);
        v = LD(rpb, off + (size_t)rel * NHd + hd, f);
    } else {
        v = -1.0e9f;
    }
    BT[idx] = v;
}

// ---- patch norm: x(B,C,H,W) -> T(B,L,C) f32 --------------------------------
__global__ __launch_bounds__(256) void k_patchnorm(const void* __restrict__ x,
                                                   const void* __restrict__ g,
                                                   const void* __restrict__ b,
                                                   float* __restrict__ T,
                                                   const int* __restrict__ dflag) {
    int f = *dflag;
    int tokid = blockIdx.x * 4 + (threadIdx.x >> 6);
    int lane  = threadIdx.x & 63;
    int bb = tokid / Ltok, ll = tokid % Ltok;
    size_t base = (size_t)bb * Cc * Ltok + ll;
    float v0 = LD(x, base + (size_t)lane * Ltok, f);
    float v1 = LD(x, base + (size_t)(lane + 64) * Ltok, f);
    float v2 = (lane < 52) ? LD(x, base + (size_t)(lane + 128) * Ltok, f) : 0.f;
    float s  = wred(v0 + v1 + v2);
    float sq = wred(v0 * v0 + v1 * v1 + v2 * v2);
    float mean = s * (1.f / 180.f);
    float var  = sq * (1.f / 180.f) - mean * mean;
    float rstd = rsqrtf(var + 1e-5f);
    float* tp = T + (size_t)tokid * Cc;
    tp[lane]      = (v0 - mean) * rstd * LD(g, lane, f)      + LD(b, lane, f);
    tp[lane + 64] = (v1 - mean) * rstd * LD(g, lane + 64, f) + LD(b, lane + 64, f);
    if (lane < 52)
        tp[lane + 128] = (v2 - mean) * rstd * LD(g, lane + 128, f) + LD(b, lane + 128, f);
}

// ---- LN (+ optional shifted-window gather) -> bf16 rows at stride KP1 ------
__global__ __launch_bounds__(256) void k_ln(const float* __restrict__ T,
                                            const void* __restrict__ g,
                                            const void* __restrict__ b,
                                            bf16* __restrict__ D,
                                            int windowed, int shift, int goff,
                                            const int* __restrict__ dflag) {
    int f = *dflag;
    int r    = blockIdx.x * 4 + (threadIdx.x >> 6);
    int lane = threadIdx.x & 63;
    int src;
    if (windowed) {
        int bb  = r / (NWIN * P49);
        int rem = r % (NWIN * P49);
        int wi = rem / P49, p = rem % P49;
        int wy = wi >> 4, wx = wi & 15;
        int py = p / 7, px = p % 7;
        int gh = (wy * 7 + py + shift) % Hh;
        int gw = (wx * 7 + px + shift) % Wwid;
        src = bb * Ltok + gh * Wwid + gw;
    } else {
        src = r;
    }
    const float* tp = T + (size_t)src * Cc;
    float v0 = tp[lane];
    float v1 = tp[lane + 64];
    float v2 = (lane < 52) ? tp[lane + 128] : 0.f;
    float s  = wred(v0 + v1 + v2);
    float sq = wred(v0 * v0 + v1 * v1 + v2 * v2);
    float mean = s * (1.f / 180.f);
    float var  = sq * (1.f / 180.f) - mean * mean;
    float rstd = rsqrtf(var + 1e-5f);
    bf16* dp = D + (size_t)r * KP1;
    dp[lane]      = (bf16)((v0 - mean) * rstd * LD(g, goff + lane, f)      + LD(b, goff + lane, f));
    dp[lane + 64] = (bf16)((v1 - mean) * rstd * LD(g, goff + lane + 64, f) + LD(b, goff + lane + 64, f));
    if (lane < 52)
        dp[lane + 128] = (bf16)((v2 - mean) * rstd * LD(g, goff + lane + 128, f) + LD(b, goff + lane + 128, f));
    else
        dp[lane + 128] = (bf16)0.f;
}

// ---- final LN -> out(B,C,H,W), out dtype per flag --------------------------
__global__ __launch_bounds__(256) void k_final(const float* __restrict__ T,
                                               const void* __restrict__ g,
                                               const void* __restrict__ b,
                                               void* __restrict__ out,
                                               const int* __restrict__ dflag) {
    int f = *dflag;
    int tokid = blockIdx.x * 4 + (threadIdx.x >> 6);
    int lane  = threadIdx.x & 63;
    int bb = tokid / Ltok, ll = tokid % Ltok;
    const float* tp = T + (size_t)tokid * Cc;
    float v0 = tp[lane];
    float v1 = tp[lane + 64];
    float v2 = (lane < 52) ? tp[lane + 128] : 0.f;
    float s  = wred(v0 + v1 + v2);
    float sq = wred(v0 * v0 + v1 * v1 + v2 * v2);
    float mean = s * (1.f / 180.f);
    float var  = sq * (1.f / 180.f) - mean * mean;
    float rstd = rsqrtf(var + 1e-5f);
    size_t base = (size_t)bb * Cc * Ltok + ll;
    ST(out, base + (size_t)lane * Ltok,        f, (v0 - mean) * rstd * LD(g, lane, f)      + LD(b, lane, f));
    ST(out, base + (size_t)(lane + 64) * Ltok, f, (v1 - mean) * rstd * LD(g, lane + 64, f) + LD(b, lane + 64, f));
    if (lane < 52)
        ST(out, base + (size_t)(lane + 128) * Ltok, f,
           (v2 - mean) * rstd * LD(g, lane + 128, f) + LD(b, lane + 128, f));
}

// ---- full-K MFMA GEMM: stage A(128x192)+W(64x192) in LDS, ONE barrier ------
// Out(M x N) = A(M x CK*192) @ Wt^T + bias. Wt (Npad x CK*192) pre-transposed.
// Block 256 thr / 4 waves in 2x2; wave covers 64 rows x 32 cols (acc 4x2).
// Staging = R5 pattern (regular loads + fragment-major ds_write, 0 conflicts),
// but all 18 global 16B loads per thread issued before one sync -> deep MLP.
// CK=4 for fc2 (K=768) loops 4 chunks (8 barriers total).
// EPI: 1 gelu+store bf16 (fc1), 2 T+= (fc2), 3 T+= shifted scatter (proj),
//      4 qkv split store (Q/K head-padded ld384 Q pre-scaled, V -> Vt).
template <int EPI, int CK>
__global__ __launch_bounds__(256, 2)
void k_fgemm(const bf16* __restrict__ A, const bf16* __restrict__ Wt,
             const void* __restrict__ bias, size_t boff, int Nbias,
             bf16* __restrict__ OutB, int ldOut, int Nstore,
             float* __restrict__ OutF, bf16* __restrict__ Vt,
             int shift, int rowoff, const int* __restrict__ dflag) {
    constexpr int LDA = CK * 192;
    __shared__ __align__(16) short Als[48 * 64 * 8];   // 48 KB: 128r x 192k
    __shared__ __align__(16) short Bls[24 * 64 * 8];   // 24 KB: 64n x 192k
    int tid = threadIdx.x, lane = tid & 63, w = tid >> 6;
    int wr = w >> 1, wc = w & 1;
    int q = lane >> 4, c = lane & 15;
    int m0 = blockIdx.y * 128, n0 = blockIdx.x * 64;
    f32x4 acc[4][2] = {};

    for (int ck = 0; ck < CK; ++ck) {
        if (ck) __syncthreads();
        // stage A: 12 x 16B per thread (slot cs = s*8+mt, row-major frag layout)
#pragma unroll
        for (int i = 0; i < 12; ++i) {
            int ri = i * 256 + tid;
            int cs = ri >> 6, ln = ri & 63;
            int s = cs >> 3, mt = cs & 7;
            const bf16* src = A + (size_t)(m0 + mt * 16 + (ln & 15)) * LDA
                              + ck * 192 + s * 32 + (ln >> 4) * 8;
            *(ulonglong2*)&Als[ri * 8] = *(const ulonglong2*)src;
        }
        // stage W: 6 x 16B per thread (slot cs = s*4+nt)
#pragma unroll
        for (int i = 0; i < 6; ++i) {
            int ri = i * 256 + tid;
            int cs = ri >> 6, ln = ri & 63;
            int s = cs >> 2, nt = cs & 3;
            const bf16* src = Wt + (size_t)(n0 + nt * 16 + (ln & 15)) * LDA
                              + ck * 192 + s * 32 + (ln >> 4) * 8;
            *(ulonglong2*)&Bls[ri * 8] = *(const ulonglong2*)src;
        }
        __syncthreads();
#pragma unroll
        for (int s = 0; s < 6; ++s) {
            short8 b0 = *(const short8*)&Bls[((s * 4 + wc * 2 + 0) * 64 + lane) * 8];
            short8 b1 = *(const short8*)&Bls[((s * 4 + wc * 2 + 1) * 64 + lane) * 8];
#pragma unroll
            for (int mt = 0; mt < 4; ++mt) {
                short8 a = *(const short8*)&Als[((s * 8 + wr * 4 + mt) * 64 + lane) * 8];
                acc[mt][0] = __builtin_amdgcn_mfma_f32_16x16x32_bf16(a, b0, acc[mt][0], 0, 0, 0);
                acc[mt][1] = __builtin_amdgcn_mfma_f32_16x16x32_bf16(a, b1, acc[mt][1], 0, 0, 0);
            }
        }
    }

    int f = *dflag;
#pragma unroll
    for (int mt = 0; mt < 4; ++mt) {
#pragma unroll
        for (int nt = 0; nt < 2; ++nt) {
#pragma unroll
            for (int r = 0; r < 4; ++r) {
                int row = m0 + (wr * 4 + mt) * 16 + q * 4 + r;   // C/D: row=(lane>>4)*4+reg
                int col = n0 + (wc * 2 + nt) * 16 + c;           //      col=lane&15
                float val = acc[mt][nt][r];
                if (EPI == 1) {
                    float bv = (col < Nbias) ? LD(bias, boff + col, f) : 0.f;
                    val += bv;
                    val = 0.5f * val * (1.f + erff(val * 0.70710678118654752f));
                    if (col < Nstore) OutB[(size_t)row * ldOut + col] = (bf16)val;
                } else if (EPI == 2) {
                    if (col < Nstore)
                        OutF[(size_t)(rowoff + row) * Cc + col] += val + LD(bias, boff + col, f);
                } else if (EPI == 3) {
                    if (col < Nstore) {
                        int grow = rowoff + row;
                        int bb  = grow / (NWIN * P49);
                        int rem = grow % (NWIN * P49);
                        int wi = rem / P49, p = rem % P49;
                        int wy = wi >> 4, wx = wi & 15;
                        int py = p / 7, px = p % 7;
                        int gh = (wy * 7 + py + shift) % Hh;
                        int gw = (wx * 7 + px + shift) % Wwid;
                        int tgt = bb * Ltok + gh * Wwid + gw;
                        OutF[(size_t)tgt * Cc + col] += val + LD(bias, boff + col, f);
                    }
                } else {  // EPI == 4: qkv
                    int sec = col / 192, rm2 = col % 192;
                    int hd = rm2 >> 5, d = rm2 & 31;
                    float bv = (d < 30) ? LD(bias, boff + sec * 180 + hd * 30 + d, f) : 0.f;
                    val += bv;
                    if (sec == 0) val *= 0.18257418583505536f;   // pre-scale Q
                    if (sec < 2) {
                        OutB[(size_t)row * 384 + sec * 192 + hd * 32 + d] = (bf16)val;
                    } else {
                        int wloc = row / 49, p = row % 49;
                        Vt[(((size_t)wloc * NHd + hd) * 32 + d) * 64 + p] = (bf16)val;
                    }
                }
            }
        }
    }
}

// ---- MFMA attention: one wave per (window, head) ---------------------------
__device__ __forceinline__ int regionOf(int g, int shift) {
    return (g < Hh - WSz) ? 0 : ((g < Hh - shift) ? 1 : 2);
}

__global__ __launch_bounds__(64) void k_mattn(const bf16* __restrict__ QK,
                                              const bf16* __restrict__ Vt,
                                              const float* __restrict__ BT,
                                              bf16* __restrict__ Ow,
                                              int shift, int w0) {
    __shared__ __align__(16) bf16 P[64 * 72];
    int lane = threadIdx.x;
    int lw = blockIdx.x / NHd, hd = blockIdx.x % NHd;
    int r0 = lw * P49;
    int q = lane >> 4, c = lane & 15;

    const bf16* qb = QK + (size_t)(r0 + c) * 384 + hd * 32 + q * 8;
    short8 qf[4], kf[4];
#pragma unroll
    for (int t = 0; t < 4; ++t) {
        qf[t] = *(const short8*)(qb + (size_t)t * 16 * 384);
        kf[t] = *(const short8*)(qb + 192 + (size_t)t * 16 * 384);
    }
    f32x4 zero = {0.f, 0.f, 0.f, 0.f};
    f32x4 S[4][4];
#pragma unroll
    for (int mt = 0; mt < 4; ++mt)
#pragma unroll
        for (int nt = 0; nt < 4; ++nt)
            S[mt][nt] = __builtin_amdgcn_mfma_f32_16x16x32_bf16(qf[mt], kf[nt], zero, 0, 0, 0);

    const float* bt = BT + hd * 4096;
    int wi = (w0 + lw) & (NWIN - 1);
    int wy = wi >> 4, wx = wi & 15;
    int lj[4], li[4][4];
    if (shift) {
#pragma unroll
        for (int nt = 0; nt < 4; ++nt) {
            int j = nt * 16 + c;
            lj[nt] = (j < 49) ? regionOf(wy * 7 + j / 7, shift) * 3 + regionOf(wx * 7 + j % 7, shift) : -1;
        }
#pragma unroll
        for (int mt = 0; mt < 4; ++mt)
#pragma unroll
            for (int r = 0; r < 4; ++r) {
                int i = mt * 16 + q * 4 + r;
                li[mt][r] = (i < 49) ? regionOf(wy * 7 + i / 7, shift) * 3 + regionOf(wx * 7 + i % 7, shift) : -2;
            }
    }
    float rmax[4][4];
#pragma unroll
    for (int mt = 0; mt < 4; ++mt)
#pragma unroll
        for (int r = 0; r < 4; ++r) rmax[mt][r] = -3.0e38f;
#pragma unroll
    for (int mt = 0; mt < 4; ++mt)
#pragma unroll
        for (int nt = 0; nt < 4; ++nt)
#pragma unroll
            for (int r = 0; r < 4; ++r) {
                int i = mt * 16 + q * 4 + r, j = nt * 16 + c;
                float v = S[mt][nt][r] + bt[i * 64 + j];
                if (shift && li[mt][r] != lj[nt]) v -= 100.f;
                S[mt][nt][r] = v;
                rmax[mt][r] = fmaxf(rmax[mt][r], v);
            }
#pragma unroll
    for (int mt = 0; mt < 4; ++mt)
#pragma unroll
        for (int r = 0; r < 4; ++r) {
            float m = rmax[mt][r];
            m = fmaxf(m, __shfl_xor(m, 1));
            m = fmaxf(m, __shfl_xor(m, 2));
            m = fmaxf(m, __shfl_xor(m, 4));
            m = fmaxf(m, __shfl_xor(m, 8));
            rmax[mt][r] = m;
        }
    float rsum[4][4] = {};
#pragma unroll
    for (int mt = 0; mt < 4; ++mt)
#pragma unroll
        for (int nt = 0; nt < 4; ++nt)
#pragma unroll
            for (int r = 0; r < 4; ++r) {
                float e = __expf(S[mt][nt][r] - rmax[mt][r]);
                S[mt][nt][r] = e;
                rsum[mt][r] += e;
            }
#pragma unroll
    for (int mt = 0; mt < 4; ++mt)
#pragma unroll
        for (int r = 0; r < 4; ++r) {
            float s = rsum[mt][r];
            s += __shfl_xor(s, 1);
            s += __shfl_xor(s, 2);
            s += __shfl_xor(s, 4);
            s += __shfl_xor(s, 8);
            rsum[mt][r] = 1.f / s;
        }
#pragma unroll
    for (int mt = 0; mt < 4; ++mt)
#pragma unroll
        for (int nt = 0; nt < 4; ++nt)
#pragma unroll
            for (int r = 0; r < 4; ++r)
                P[(mt * 16 + q * 4 + r) * 72 + nt * 16 + c] = (bf16)(S[mt][nt][r] * rsum[mt][r]);
    __syncthreads();

    f32x4 O[4][2] = {};
    const bf16* vb = Vt + (((size_t)lw * NHd + hd) * 32 + c) * 64 + q * 8;
#pragma unroll
    for (int ks = 0; ks < 2; ++ks) {
        short8 vf0 = *(const short8*)(vb + ks * 32);
        short8 vf1 = *(const short8*)(vb + 16 * 64 + ks * 32);
#pragma unroll
        for (int mt = 0; mt < 4; ++mt) {
            short8 pf = *(const short8*)&P[(mt * 16 + c) * 72 + ks * 32 + q * 8];
            O[mt][0] = __builtin_amdgcn_mfma_f32_16x16x32_bf16(pf, vf0, O[mt][0], 0, 0, 0);
            O[mt][1] = __builtin_amdgcn_mfma_f32_16x16x32_bf16(pf, vf1, O[mt][1], 0, 0, 0);
        }
    }
    int r0g = (w0 + lw) * P49;
#pragma unroll
    for (int mt = 0; mt < 4; ++mt)
#pragma unroll
        for (int nt = 0; nt < 2; ++nt)
#pragma unroll
            for (int r = 0; r < 4; ++r) {
                int i = mt * 16 + q * 4 + r, d = nt * 16 + c;
                if (i < 49 && d < 30)
                    Ow[(size_t)(r0g + i) * KP1 + hd * 30 + d] = (bf16)O[mt][nt][r];
            }
    if (hd == 0) {
        for (int idx = lane; idx < P49 * 12; idx += 64) {
            int p = idx / 12, cp = 180 + idx % 12;
            Ow[(size_t)(r0g + p) * KP1 + cp] = (bf16)0.f;
        }
    }
}

// ---------------------------------------------------------------------------
extern "C" void kernel_launch(void* const* d_in, const int* in_sizes, int n_in,
                              void* d_out, int out_size, void* d_ws, size_t ws_size,
                              hipStream_t stream) {
    const void* x      = d_in[0];
    const void* pe_g   = d_in[1];
    const void* pe_b   = d_in[2];
    const void* ln1_g  = d_in[3];
    const void* ln1_b  = d_in[4];
    const void* qkv_w  = d_in[5];
    const void* qkv_b  = d_in[6];
    const void* proj_w = d_in[7];
    const void* proj_b = d_in[8];
    const void* ln2_g  = d_in[9];
    const void* ln2_b  = d_in[10];
    const void* fc1_w  = d_in[11];
    const void* fc1_b  = d_in[12];
    const void* fc2_w  = d_in[13];
    const void* fc2_b  = d_in[14];
    const void* rpb    = d_in[15];
    const void* fn_g   = d_in[16];
    const void* fn_b   = d_in[17];

    const size_t wtQ = (size_t)576 * KP1, wtP = (size_t)192 * KP1;
    const size_t wtF1 = (size_t)768 * KP1, wtF2 = (size_t)192 * KP2;
    const size_t wtPerBlk = wtQ + wtP + wtF1 + wtF2;

    int*   dflag = (int*)d_ws;
    float* T     = (float*)((char*)d_ws + 256);
    bf16*  Abuf  = (bf16*)(T + (size_t)TOK * Cc);
    bf16*  Wts   = Abuf + (size_t)TOK * KP1;
    float* BT    = (float*)(Wts + 4 * wtPerBlk);
    bf16*  Vt    = (bf16*)(BT + NHd * 4096);
    size_t fixed = (size_t)((char*)Vt - (char*)d_ws);

    int c = 1;   // chunks; CM stays a multiple of 128 for c in {1,2,4}
    while (c < 4 && fixed + ((size_t)(Bsz * NWIN / c) * NHd * 32 * 64
                             + (size_t)(TOK / c) * KP2) * 2 > ws_size) c <<= 1;
    int CM = TOK / c;
    int CW = (Bsz * NWIN) / c;
    bf16* Bbuf = Vt + (size_t)CW * NHd * 32 * 64;   // QK (ld384) / fc1 out (ld768)

    dim3 b256(256);
    k_detect<<<1, b256, 0, stream>>>((const unsigned short*)x, dflag);

    for (int i = 0; i < 4; ++i) {
        bf16* wq  = Wts + i * wtPerBlk;
        bf16* wp  = wq + wtQ;
        bf16* wf1 = wp + wtP;
        bf16* wf2 = wf1 + wtF1;
        k_trq<<<(int)((wtQ + 255) / 256), b256, 0, stream>>>(qkv_w, (size_t)i * Cc * 540, wq, dflag);
        k_tr<<<(int)((wtP  + 255) / 256), b256, 0, stream>>>(proj_w, (size_t)i * Cc * Cc,  wp,  180, 180, KP1, 192, dflag);
        k_tr<<<(int)((wtF1 + 255) / 256), b256, 0, stream>>>(fc1_w,  (size_t)i * Cc * 720, wf1, 180, 720, KP1, 768, dflag);
        k_tr<<<(int)((wtF2 + 255) / 256), b256, 0, stream>>>(fc2_w,  (size_t)i * 720 * Cc, wf2, 720, 180, KP2, 192, dflag);
    }

    k_patchnorm<<<TOK / 4, b256, 0, stream>>>(x, pe_g, pe_b, T, dflag);

    const int shifts[4] = {0, 3, 0, 3};
    for (int i = 0; i < 4; ++i) {
        int sh = shifts[i];
        bf16* wq  = Wts + i * wtPerBlk;
        bf16* wp  = wq + wtQ;
        bf16* wf1 = wp + wtP;
        bf16* wf2 = wf1 + wtF1;

        k_bias<<<(NHd * 4096 + 255) / 256, b256, 0, stream>>>(rpb, (size_t)i * 169 * NHd, BT, dflag);
        k_ln<<<TOK / 4, b256, 0, stream>>>(T, ln1_g, ln1_b, Abuf, 1, sh, i * Cc, dflag);
        for (int j = 0; j < c; ++j) {
            int R0 = j * CM;
            k_fgemm<4, 1><<<dim3(9, CM / 128), b256, 0, stream>>>(
                Abuf + (size_t)R0 * KP1, wq, qkv_b, (size_t)i * 540, 540,
                Bbuf, 384, 576, nullptr, Vt, 0, 0, dflag);
            k_mattn<<<CW * NHd, 64, 0, stream>>>(Bbuf, Vt, BT, Abuf, sh, j * CW);
            k_fgemm<3, 1><<<dim3(3, CM / 128), b256, 0, stream>>>(
                Abuf + (size_t)R0 * KP1, wp, proj_b, (size_t)i * Cc, Cc,
                nullptr, 0, Cc, T, nullptr, sh, R0, dflag);
        }
        k_ln<<<TOK / 4, b256, 0, stream>>>(T, ln2_g, ln2_b, Abuf, 0, 0, i * Cc, dflag);
        for (int j = 0; j < c; ++j) {
            int R0 = j * CM;
            k_fgemm<1, 1><<<dim3(12, CM / 128), b256, 0, stream>>>(
                Abuf + (size_t)R0 * KP1, wf1, fc1_b, (size_t)i * 720, 720,
                Bbuf, KP2, KP2, nullptr, nullptr, 0, 0, dflag);
            k_fgemm<2, 4><<<dim3(3, CM / 128), b256, 0, stream>>>(
                Bbuf, wf2, fc2_b, (size_t)i * Cc, Cc,
                nullptr, 0, Cc, T, nullptr, 0, R0, dflag);
        }
    }

    k_final<<<TOK / 4, b256, 0, stream>>>(T, fn_g, fn_b, d_out, dflag);
}

// Round 9
// 941.476 us; speedup vs baseline: 1.2671x; 1.2671x over previous
//
#include <hip/hip_runtime.h>
#include <hip/hip_bf16.h>
#include <cmath>

typedef __hip_bfloat16 bf16;
typedef short short8 __attribute__((ext_vector_type(8)));   // 8 bf16 (4 VGPRs)
typedef float f32x4  __attribute__((ext_vector_type(4)));   // MFMA acc

#define Cc    180
#define KP1   192      // 180 padded to mult of 32
#define KP2   736      // 720 padded to mult of 32
#define Hh    112
#define Wwid  112
#define Ltok  12544
#define Bsz   2
#define TOK   25088
#define WSz   7
#define NHd   6
#define DHd   30
#define NWIN  256
#define P49   49

// Dual-dtype input access: flag==1 -> float32 inputs, flag==0 -> bf16.
__device__ __forceinline__ float LD(const void* p, size_t i, int f) {
    if (f) return ((const float*)p)[i];
    return (float)((const bf16*)p)[i];
}
__device__ __forceinline__ void ST(void* p, size_t i, int f, float v) {
    if (f) ((float*)p)[i] = v;
    else   ((bf16*)p)[i] = (bf16)v;
}

__device__ __forceinline__ short bh(float x) { bf16 t = (bf16)x; return *(short*)&t; }
__device__ __forceinline__ short8 cvt8(float4 a, float4 b) {
    short8 o;
    o[0] = bh(a.x); o[1] = bh(a.y); o[2] = bh(a.z); o[3] = bh(a.w);
    o[4] = bh(b.x); o[5] = bh(b.y); o[6] = bh(b.z); o[7] = bh(b.w);
    return o;
}

__device__ __forceinline__ float wred(float v) {
    v += __shfl_xor(v, 1);
    v += __shfl_xor(v, 2);
    v += __shfl_xor(v, 4);
    v += __shfl_xor(v, 8);
    v += __shfl_xor(v, 16);
    v += __shfl_xor(v, 32);
    return v;
}

// ---- dtype detect (bf16 N(0,1) never has exponent >= 0xC8) -----------------
__global__ void k_detect(const unsigned short* __restrict__ xb, int* __restrict__ flag) {
    __shared__ int s;
    if (threadIdx.x == 0) s = 0;
    __syncthreads();
    int bad = 0;
    for (int i = threadIdx.x; i < 2048; i += 256) {
        int e = (xb[i] >> 7) & 0xFF;
        if (e >= 0xC8) bad = 1;
    }
    if (bad) atomicOr(&s, 1);
    __syncthreads();
    if (threadIdx.x == 0) flag[0] = s;
}

// ---- weight transpose+pad: dst(Npad x Kp) <- src(K x N), zeros outside -----
__global__ __launch_bounds__(256) void k_tr(const void* __restrict__ src, size_t woff,
                                            bf16* __restrict__ dst,
                                            int K, int N, int Kp, int Npad,
                                            const int* __restrict__ dflag) {
    int f = *dflag;
    int idx = blockIdx.x * 256 + threadIdx.x;
    if (idx >= Npad * Kp) return;
    int n = idx / Kp, k = idx % Kp;
    float v = (n < N && k < K) ? LD(src, woff + (size_t)k * N + n, f) : 0.f;
    dst[idx] = (bf16)v;
}

// ---- qkv weight transpose with head-padded column remap --------------------
__global__ __launch_bounds__(256) void k_trq(const void* __restrict__ src, size_t woff,
                                             bf16* __restrict__ dst,
                                             const int* __restrict__ dflag) {
    int f = *dflag;
    int idx = blockIdx.x * 256 + threadIdx.x;
    if (idx >= 576 * KP1) return;
    int n = idx / KP1, k = idx % KP1;
    int sec = n / 192, rm = n % 192, hd = rm >> 5, d = rm & 31;
    float v = (d < 30 && k < 180) ? LD(src, woff + (size_t)k * 540 + sec * 180 + hd * 30 + d, f) : 0.f;
    dst[idx] = (bf16)v;
}

// ---- rpb expand for ALL 4 blocks: BT[4][6][64][64] f32, -1e9 in pads -------
__global__ __launch_bounds__(256) void k_bias(const void* __restrict__ rpb,
                                              float* __restrict__ BT,
                                              const int* __restrict__ dflag) {
    int f = *dflag;
    int idx = blockIdx.x * 256 + threadIdx.x;
    if (idx >= 4 * NHd * 4096) return;
    int blk = idx / (NHd * 4096);
    int rem0 = idx % (NHd * 4096);
    int hd = rem0 >> 12, rem = rem0 & 4095;
    int i = rem >> 6, j = rem & 63;
    float v;
    if (i < 49 && j < 49) {
        int rel = (i / 7 - j / 7 + 6) * 13 + (i % 7 - j % 7 + 6);
        v = LD(rpb, (size_t)blk * 169 * NHd + (size_t)rel * NHd + hd, f);
    } else {
        v = -1.0e9f;
    }
    BT[idx] = v;
}

// ---- patch norm: x(B,C,H,W) -> T(B,L,C) f32 --------------------------------
__global__ __launch_bounds__(256) void k_patchnorm(const void* __restrict__ x,
                                                   const void* __restrict__ g,
                                                   const void* __restrict__ b,
                                                   float* __restrict__ T,
                                                   const int* __restrict__ dflag) {
    int f = *dflag;
    int tokid = blockIdx.x * 4 + (threadIdx.x >> 6);
    int lane  = threadIdx.x & 63;
    int bb = tokid / Ltok, ll = tokid % Ltok;
    size_t base = (size_t)bb * Cc * Ltok + ll;
    float v0 = LD(x, base + (size_t)lane * Ltok, f);
    float v1 = LD(x, base + (size_t)(lane + 64) * Ltok, f);
    float v2 = (lane < 52) ? LD(x, base + (size_t)(lane + 128) * Ltok, f) : 0.f;
    float s  = wred(v0 + v1 + v2);
    float sq = wred(v0 * v0 + v1 * v1 + v2 * v2);
    float mean = s * (1.f / 180.f);
    float var  = sq * (1.f / 180.f) - mean * mean;
    float rstd = rsqrtf(var + 1e-5f);
    float* tp = T + (size_t)tokid * Cc;
    tp[lane]      = (v0 - mean) * rstd * LD(g, lane, f)      + LD(b, lane, f);
    tp[lane + 64] = (v1 - mean) * rstd * LD(g, lane + 64, f) + LD(b, lane + 64, f);
    if (lane < 52)
        tp[lane + 128] = (v2 - mean) * rstd * LD(g, lane + 128, f) + LD(b, lane + 128, f);
}

// ---- LN (+ optional shifted-window gather) -> bf16 rows at stride KP1 ------
__global__ __launch_bounds__(256) void k_ln(const float* __restrict__ T,
                                            const void* __restrict__ g,
                                            const void* __restrict__ b,
                                            bf16* __restrict__ D,
                                            int windowed, int shift, int goff,
                                            const int* __restrict__ dflag) {
    int f = *dflag;
    int r    = blockIdx.x * 4 + (threadIdx.x >> 6);
    int lane = threadIdx.x & 63;
    int src;
    if (windowed) {
        int bb  = r / (NWIN * P49);
        int rem = r % (NWIN * P49);
        int wi = rem / P49, p = rem % P49;
        int wy = wi >> 4, wx = wi & 15;
        int py = p / 7, px = p % 7;
        int gh = (wy * 7 + py + shift) % Hh;
        int gw = (wx * 7 + px + shift) % Wwid;
        src = bb * Ltok + gh * Wwid + gw;
    } else {
        src = r;
    }
    const float* tp = T + (size_t)src * Cc;
    float v0 = tp[lane];
    float v1 = tp[lane + 64];
    float v2 = (lane < 52) ? tp[lane + 128] : 0.f;
    float s  = wred(v0 + v1 + v2);
    float sq = wred(v0 * v0 + v1 * v1 + v2 * v2);
    float mean = s * (1.f / 180.f);
    float var  = sq * (1.f / 180.f) - mean * mean;
    float rstd = rsqrtf(var + 1e-5f);
    bf16* dp = D + (size_t)r * KP1;
    dp[lane]      = (bf16)((v0 - mean) * rstd * LD(g, goff + lane, f)      + LD(b, goff + lane, f));
    dp[lane + 64] = (bf16)((v1 - mean) * rstd * LD(g, goff + lane + 64, f) + LD(b, goff + lane + 64, f));
    if (lane < 52)
        dp[lane + 128] = (bf16)((v2 - mean) * rstd * LD(g, goff + lane + 128, f) + LD(b, goff + lane + 128, f));
    else
        dp[lane + 128] = (bf16)0.f;
}

// ---- final LN -> out(B,C,H,W), out dtype per flag --------------------------
__global__ __launch_bounds__(256) void k_final(const float* __restrict__ T,
                                               const void* __restrict__ g,
                                               const void* __restrict__ b,
                                               void* __restrict__ out,
                                               const int* __restrict__ dflag) {
    int f = *dflag;
    int tokid = blockIdx.x * 4 + (threadIdx.x >> 6);
    int lane  = threadIdx.x & 63;
    int bb = tokid / Ltok, ll = tokid % Ltok;
    const float* tp = T + (size_t)tokid * Cc;
    float v0 = tp[lane];
    float v1 = tp[lane + 64];
    float v2 = (lane < 52) ? tp[lane + 128] : 0.f;
    float s  = wred(v0 + v1 + v2);
    float sq = wred(v0 * v0 + v1 * v1 + v2 * v2);
    float mean = s * (1.f / 180.f);
    float var  = sq * (1.f / 180.f) - mean * mean;
    float rstd = rsqrtf(var + 1e-5f);
    size_t base = (size_t)bb * Cc * Ltok + ll;
    ST(out, base + (size_t)lane * Ltok,        f, (v0 - mean) * rstd * LD(g, lane, f)      + LD(b, lane, f));
    ST(out, base + (size_t)(lane + 64) * Ltok, f, (v1 - mean) * rstd * LD(g, lane + 64, f) + LD(b, lane + 64, f));
    if (lane < 52)
        ST(out, base + (size_t)(lane + 128) * Ltok, f,
           (v2 - mean) * rstd * LD(g, lane + 128, f) + LD(b, lane + 128, f));
}

// ---- MFMA GEMM (R5 core + register prefetch + coalesced LDS epilogue) ------
// Out(M x N) = A(M x Kp bf16) @ Wt^T + bias. Wt (Npad x Kp) pre-transposed.
// Block 256 thr / 4 waves 2x2, tile 128x64, BK=32. Staging regs prefetched
// one iter ahead (global latency overlaps MFMA+ds_read). Epilogue routes acc
// through f32 LDS [64][72] (2 passes) -> 16B coalesced stores / float4 RMW.
// EPI: 1 gelu+store bf16 (fc1), 2 T+= (fc2), 3 T+= shifted scatter (proj),
//      4 qkv store ld 576 (Q scaled + head-remapped bias; V plain 3rd seg).
template <int EPI>
__global__ __launch_bounds__(256) void k_mgemm(const bf16* __restrict__ A,
                                               const bf16* __restrict__ Wt,
                                               const void* __restrict__ bias,
                                               size_t boff, int Nbias,
                                               bf16* __restrict__ OutB, int ldOut, int Nstore,
                                               float* __restrict__ OutF,
                                               int Kp, int shift, int rowoff,
                                               const int* __restrict__ dflag) {
    __shared__ __align__(16) char SM[64 * 72 * 4];     // 18.4 KB (union)
    short* Als = (short*)SM;                           // 8 KB staging A
    short* Bls = (short*)(SM + 8192);                  // 4 KB staging W
    float* Els = (float*)SM;                           // epilogue tile
    int tid = threadIdx.x, lane = tid & 63, w = tid >> 6;
    int wr = w >> 1, wc = w & 1;
    int q = lane >> 4, c = lane & 15;
    int m0 = blockIdx.y * 128, n0 = blockIdx.x * 64;
    f32x4 acc[4][2] = {};

    // prefetch pointers (R5 slot mapping)
    int rowA0 = m0 + (tid >> 6) * 16 + (tid & 15);
    int rowW  = n0 + (tid >> 6) * 16 + (tid & 15);
    int koff  = ((tid >> 4) & 3) * 8;
    const bf16* pa0 = A + (size_t)rowA0 * Kp + koff;
    const bf16* pa1 = A + (size_t)(rowA0 + 64) * Kp + koff;
    const bf16* pw  = Wt + (size_t)rowW * Kp + koff;
    ulonglong2 rA0 = *(const ulonglong2*)pa0;
    ulonglong2 rA1 = *(const ulonglong2*)pa1;
    ulonglong2 rW  = *(const ulonglong2*)pw;

    for (int k0 = 0; k0 < Kp; k0 += 32) {
        *(ulonglong2*)&Als[tid * 8]         = rA0;
        *(ulonglong2*)&Als[(tid + 256) * 8] = rA1;
        *(ulonglong2*)&Bls[tid * 8]         = rW;
        __syncthreads();
        if (k0 + 32 < Kp) {                 // prefetch next iter (overlaps MFMA)
            rA0 = *(const ulonglong2*)(pa0 + k0 + 32);
            rA1 = *(const ulonglong2*)(pa1 + k0 + 32);
            rW  = *(const ulonglong2*)(pw  + k0 + 32);
        }
        short8 b0 = *(const short8*)&Bls[((wc * 2 + 0) * 64 + lane) * 8];
        short8 b1 = *(const short8*)&Bls[((wc * 2 + 1) * 64 + lane) * 8];
#pragma unroll
        for (int mt = 0; mt < 4; ++mt) {
            short8 a = *(const short8*)&Als[((wr * 4 + mt) * 64 + lane) * 8];
            acc[mt][0] = __builtin_amdgcn_mfma_f32_16x16x32_bf16(a, b0, acc[mt][0], 0, 0, 0);
            acc[mt][1] = __builtin_amdgcn_mfma_f32_16x16x32_bf16(a, b1, acc[mt][1], 0, 0, 0);
        }
        __syncthreads();
    }

    int f = *dflag;
#pragma unroll
    for (int Ph = 0; Ph < 2; ++Ph) {
        if (Ph) __syncthreads();
        if (wr == Ph) {
#pragma unroll
            for (int mt = 0; mt < 4; ++mt)
#pragma unroll
                for (int nt = 0; nt < 2; ++nt)
#pragma unroll
                    for (int r = 0; r < 4; ++r) {
                        int rl = mt * 16 + q * 4 + r;           // C/D row=(lane>>4)*4+reg
                        int cl = (wc * 2 + nt) * 16 + c;        // col=lane&15
                        int col = n0 + cl;
                        float val = acc[mt][nt][r];
                        if (EPI == 4) {
                            int sec = col / 192, rm = col % 192;
                            int hd = rm >> 5, d = rm & 31;
                            if (d < 30) val += LD(bias, boff + sec * 180 + hd * 30 + d, f);
                            if (sec == 0) val *= 0.18257418583505536f;   // pre-scale Q
                        } else if (EPI == 1) {
                            if (col < Nbias) val += LD(bias, boff + col, f);
                            val = 0.5f * val * (1.f + erff(val * 0.70710678118654752f));
                        } else {
                            if (col < Nstore) val += LD(bias, boff + col, f);
                        }
                        Els[rl * 72 + cl] = val;
                    }
        }
        __syncthreads();
        if (EPI == 1 || EPI == 4) {
#pragma unroll
            for (int it = 0; it < 2; ++it) {
                int ri = it * 256 + tid;
                int row = ri >> 3, c8 = ri & 7;
                int gcol = n0 + c8 * 8;
                if (gcol < Nstore) {
                    float4 v0 = *(float4*)&Els[row * 72 + c8 * 8];
                    float4 v1 = *(float4*)&Els[row * 72 + c8 * 8 + 4];
                    short8 o = cvt8(v0, v1);
                    *(ulonglong2*)(OutB + (size_t)(m0 + Ph * 64 + row) * ldOut + gcol) =
                        *(ulonglong2*)&o;
                }
            }
        } else {   // EPI 2/3: coalesced float4 RMW into residual T
#pragma unroll
            for (int it = 0; it < 4; ++it) {
                int ri = it * 256 + tid;
                int row = ri >> 4, c4 = ri & 15;
                int col = n0 + c4 * 4;
                if (col < Nstore) {
                    int grow = rowoff + m0 + Ph * 64 + row;
                    int tgt = grow;
                    if (EPI == 3) {
                        int bb  = grow / (NWIN * P49);
                        int rem = grow % (NWIN * P49);
                        int wi = rem / P49, p = rem % P49;
                        int wy = wi >> 4, wx = wi & 15;
                        int py = p / 7, px = p % 7;
                        int gh = (wy * 7 + py + shift) % Hh;
                        int gw = (wx * 7 + px + shift) % Wwid;
                        tgt = bb * Ltok + gh * Wwid + gw;
                    }
                    float4* tp = (float4*)(OutF + (size_t)tgt * Cc + col);
                    float4 t = *tp;
                    float4 e = *(float4*)&Els[row * 72 + c4 * 4];
                    t.x += e.x; t.y += e.y; t.z += e.z; t.w += e.w;
                    *tp = t;
                }
            }
        }
    }
}

// ---- MFMA attention: one wave per (window, head); V transposed in LDS ------
__device__ __forceinline__ int regionOf(int g, int shift) {
    return (g < Hh - WSz) ? 0 : ((g < Hh - shift) ? 1 : 2);
}

__global__ __launch_bounds__(64) void k_mattn(const bf16* __restrict__ QKV,
                                              const bf16* __restrict__ Vt_unused,
                                              const float* __restrict__ BT,
                                              bf16* __restrict__ Ow,
                                              int shift, int w0) {
    __shared__ __align__(16) bf16 P[64 * 72];
    __shared__ __align__(16) bf16 Vl[32 * 72];
    int lane = threadIdx.x;
    int lw = blockIdx.x / NHd, hd = blockIdx.x % NHd;
    int r0 = lw * P49;
    int q = lane >> 4, c = lane & 15;

    // Q/K fragments from global (ld 576)
    const bf16* qb = QKV + (size_t)(r0 + c) * 576 + hd * 32 + q * 8;
    short8 qf[4], kf[4];
#pragma unroll
    for (int t = 0; t < 4; ++t) {
        qf[t] = *(const short8*)(qb + (size_t)t * 16 * 576);
        kf[t] = *(const short8*)(qb + 192 + (size_t)t * 16 * 576);
    }
    // stage V^T into LDS: Vl[d][p], zeros for p>=49
    for (int t = lane; t < 32 * 15; t += 64) {
        int d = t / 15, p = 49 + t % 15;
        Vl[d * 72 + p] = (bf16)0.f;
    }
    for (int t = lane; t < P49 * 4; t += 64) {
        int p = t >> 2, ch = t & 3;
        ulonglong2 v = *(const ulonglong2*)(QKV + (size_t)(r0 + p) * 576 + 384 + hd * 32 + ch * 8);
        bf16* vv = (bf16*)&v;
#pragma unroll
        for (int j = 0; j < 8; ++j) Vl[(ch * 8 + j) * 72 + p] = vv[j];
    }

    f32x4 zero = {0.f, 0.f, 0.f, 0.f};
    f32x4 S[4][4];
#pragma unroll
    for (int mt = 0; mt < 4; ++mt)
#pragma unroll
        for (int nt = 0; nt < 4; ++nt)
            S[mt][nt] = __builtin_amdgcn_mfma_f32_16x16x32_bf16(qf[mt], kf[nt], zero, 0, 0, 0);

    const float* bt = BT + hd * 4096;
    int wi = (w0 + lw) & (NWIN - 1);
    int wy = wi >> 4, wx = wi & 15;
    int lj[4], li[4][4];
    if (shift) {
#pragma unroll
        for (int nt = 0; nt < 4; ++nt) {
            int j = nt * 16 + c;
            lj[nt] = (j < 49) ? regionOf(wy * 7 + j / 7, shift) * 3 + regionOf(wx * 7 + j % 7, shift) : -1;
        }
#pragma unroll
        for (int mt = 0; mt < 4; ++mt)
#pragma unroll
            for (int r = 0; r < 4; ++r) {
                int i = mt * 16 + q * 4 + r;
                li[mt][r] = (i < 49) ? regionOf(wy * 7 + i / 7, shift) * 3 + regionOf(wx * 7 + i % 7, shift) : -2;
            }
    }
    float rmax[4][4];
#pragma unroll
    for (int mt = 0; mt < 4; ++mt)
#pragma unroll
        for (int r = 0; r < 4; ++r) rmax[mt][r] = -3.0e38f;
#pragma unroll
    for (int mt = 0; mt < 4; ++mt)
#pragma unroll
        for (int nt = 0; nt < 4; ++nt)
#pragma unroll
            for (int r = 0; r < 4; ++r) {
                int i = mt * 16 + q * 4 + r, j = nt * 16 + c;
                float v = S[mt][nt][r] + bt[i * 64 + j];
                if (shift && li[mt][r] != lj[nt]) v -= 100.f;
                S[mt][nt][r] = v;
                rmax[mt][r] = fmaxf(rmax[mt][r], v);
            }
#pragma unroll
    for (int mt = 0; mt < 4; ++mt)
#pragma unroll
        for (int r = 0; r < 4; ++r) {
            float m = rmax[mt][r];
            m = fmaxf(m, __shfl_xor(m, 1));
            m = fmaxf(m, __shfl_xor(m, 2));
            m = fmaxf(m, __shfl_xor(m, 4));
            m = fmaxf(m, __shfl_xor(m, 8));
            rmax[mt][r] = m;
        }
    float rsum[4][4] = {};
#pragma unroll
    for (int mt = 0; mt < 4; ++mt)
#pragma unroll
        for (int nt = 0; nt < 4; ++nt)
#pragma unroll
            for (int r = 0; r < 4; ++r) {
                float e = __expf(S[mt][nt][r] - rmax[mt][r]);
                S[mt][nt][r] = e;
                rsum[mt][r] += e;
            }
#pragma unroll
    for (int mt = 0; mt < 4; ++mt)
#pragma unroll
        for (int r = 0; r < 4; ++r) {
            float s = rsum[mt][r];
            s += __shfl_xor(s, 1);
            s += __shfl_xor(s, 2);
            s += __shfl_xor(s, 4);
            s += __shfl_xor(s, 8);
            rsum[mt][r] = 1.f / s;
        }
#pragma unroll
    for (int mt = 0; mt < 4; ++mt)
#pragma unroll
        for (int nt = 0; nt < 4; ++nt)
#pragma unroll
            for (int r = 0; r < 4; ++r)
                P[(mt * 16 + q * 4 + r) * 72 + nt * 16 + c] = (bf16)(S[mt][nt][r] * rsum[mt][r]);
    __syncthreads();   // P + Vl ready

    f32x4 O[4][2] = {};
#pragma unroll
    for (int ks = 0; ks < 2; ++ks) {
        short8 vf0 = *(const short8*)&Vl[(0  + c) * 72 + ks * 32 + q * 8];
        short8 vf1 = *(const short8*)&Vl[(16 + c) * 72 + ks * 32 + q * 8];
#pragma unroll
        for (int mt = 0; mt < 4; ++mt) {
            short8 pf = *(const short8*)&P[(mt * 16 + c) * 72 + ks * 32 + q * 8];
            O[mt][0] = __builtin_amdgcn_mfma_f32_16x16x32_bf16(pf, vf0, O[mt][0], 0, 0, 0);
            O[mt][1] = __builtin_amdgcn_mfma_f32_16x16x32_bf16(pf, vf1, O[mt][1], 0, 0, 0);
        }
    }
    int r0g = (w0 + lw) * P49;
#pragma unroll
    for (int mt = 0; mt < 4; ++mt)
#pragma unroll
        for (int nt = 0; nt < 2; ++nt)
#pragma unroll
            for (int r = 0; r < 4; ++r) {
                int i = mt * 16 + q * 4 + r, d = nt * 16 + c;
                if (i < 49 && d < 30)
                    Ow[(size_t)(r0g + i) * KP1 + hd * 30 + d] = (bf16)O[mt][nt][r];
            }
    if (hd == 0) {
        for (int idx = lane; idx < P49 * 12; idx += 64) {
            int p = idx / 12, cp = 180 + idx % 12;
            Ow[(size_t)(r0g + p) * KP1 + cp] = (bf16)0.f;
        }
    }
}

// ---------------------------------------------------------------------------
extern "C" void kernel_launch(void* const* d_in, const int* in_sizes, int n_in,
                              void* d_out, int out_size, void* d_ws, size_t ws_size,
                              hipStream_t stream) {
    const void* x      = d_in[0];
    const void* pe_g   = d_in[1];
    const void* pe_b   = d_in[2];
    const void* ln1_g  = d_in[3];
    const void* ln1_b  = d_in[4];
    const void* qkv_w  = d_in[5];
    const void* qkv_b  = d_in[6];
    const void* proj_w = d_in[7];
    const void* proj_b = d_in[8];
    const void* ln2_g  = d_in[9];
    const void* ln2_b  = d_in[10];
    const void* fc1_w  = d_in[11];
    const void* fc1_b  = d_in[12];
    const void* fc2_w  = d_in[13];
    const void* fc2_b  = d_in[14];
    const void* rpb    = d_in[15];
    const void* fn_g   = d_in[16];
    const void* fn_b   = d_in[17];

    const size_t wtQ = (size_t)576 * KP1, wtP = (size_t)192 * KP1;
    const size_t wtF1 = (size_t)768 * KP1, wtF2 = (size_t)192 * KP2;
    const size_t wtPerBlk = wtQ + wtP + wtF1 + wtF2;

    int*   dflag = (int*)d_ws;
    float* T     = (float*)((char*)d_ws + 256);
    bf16*  Abuf  = (bf16*)(T + (size_t)TOK * Cc);
    bf16*  Wts   = Abuf + (size_t)TOK * KP1;
    float* BT4   = (float*)(Wts + 4 * wtPerBlk);       // 4 x 6 x 64 x 64 f32
    bf16*  Bbuf  = (bf16*)(BT4 + 4 * NHd * 4096);
    size_t fixed = (size_t)((char*)Bbuf - (char*)d_ws);

    int c = 1;   // chunks; CM stays a multiple of 128 for c in {1,2,4}
    while (c < 4 && fixed + (size_t)(TOK / c) * KP2 * 2 > ws_size) c <<= 1;
    int CM = TOK / c;
    int CW = (Bsz * NWIN) / c;

    dim3 b256(256);
    k_detect<<<1, b256, 0, stream>>>((const unsigned short*)x, dflag);

    for (int i = 0; i < 4; ++i) {
        bf16* wq  = Wts + i * wtPerBlk;
        bf16* wp  = wq + wtQ;
        bf16* wf1 = wp + wtP;
        bf16* wf2 = wf1 + wtF1;
        k_trq<<<(int)((wtQ + 255) / 256), b256, 0, stream>>>(qkv_w, (size_t)i * Cc * 540, wq, dflag);
        k_tr<<<(int)((wtP  + 255) / 256), b256, 0, stream>>>(proj_w, (size_t)i * Cc * Cc,  wp,  180, 180, KP1, 192, dflag);
        k_tr<<<(int)((wtF1 + 255) / 256), b256, 0, stream>>>(fc1_w,  (size_t)i * Cc * 720, wf1, 180, 720, KP1, 768, dflag);
        k_tr<<<(int)((wtF2 + 255) / 256), b256, 0, stream>>>(fc2_w,  (size_t)i * 720 * Cc, wf2, 720, 180, KP2, 192, dflag);
    }
    k_bias<<<(4 * NHd * 4096 + 255) / 256, b256, 0, stream>>>(rpb, BT4, dflag);

    k_patchnorm<<<TOK / 4, b256, 0, stream>>>(x, pe_g, pe_b, T, dflag);

    const int shifts[4] = {0, 3, 0, 3};
    for (int i = 0; i < 4; ++i) {
        int sh = shifts[i];
        bf16* wq  = Wts + i * wtPerBlk;
        bf16* wp  = wq + wtQ;
        bf16* wf1 = wp + wtP;
        bf16* wf2 = wf1 + wtF1;

        k_ln<<<TOK / 4, b256, 0, stream>>>(T, ln1_g, ln1_b, Abuf, 1, sh, i * Cc, dflag);
        for (int j = 0; j < c; ++j) {
            int R0 = j * CM;
            k_mgemm<4><<<dim3(9, CM / 128), b256, 0, stream>>>(
                Abuf + (size_t)R0 * KP1, wq, qkv_b, (size_t)i * 540, 540,
                Bbuf, 576, 576, nullptr, KP1, 0, 0, dflag);
            k_mattn<<<CW * NHd, 64, 0, stream>>>(Bbuf, nullptr, BT4 + i * NHd * 4096,
                                                 Abuf, sh, j * CW);
            k_mgemm<3><<<dim3(3, CM / 128), b256, 0, stream>>>(
                Abuf + (size_t)R0 * KP1, wp, proj_b, (size_t)i * Cc, Cc,
                nullptr, 0, Cc, T, KP1, sh, R0, dflag);
        }
        k_ln<<<TOK / 4, b256, 0, stream>>>(T, ln2_g, ln2_b, Abuf, 0, 0, i * Cc, dflag);
        for (int j = 0; j < c; ++j) {
            int R0 = j * CM;
            k_mgemm<1><<<dim3(12, CM / 128), b256, 0, stream>>>(
                Abuf + (size_t)R0 * KP1, wf1, fc1_b, (size_t)i * 720, 720,
                Bbuf, KP2, KP2, nullptr, KP1, 0, 0, dflag);
            k_mgemm<2><<<dim3(3, CM / 128), b256, 0, stream>>>(
                Bbuf, wf2, fc2_b, (size_t)i * Cc, Cc,
                nullptr, 0, Cc, T, KP2, 0, R0, dflag);
        }
    }

    k_final<<<TOK / 4, b256, 0, stream>>>(T, fn_g, fn_b, d_out, dflag);
}